// Round 11
// baseline (227.968 us; speedup 1.0000x reference)
//
#include <hip/hip_runtime.h>
#include <hip/hip_cooperative_groups.h>
#include <math.h>

namespace cg = cooperative_groups;

// Problem constants (Qwen3-4B-like decode)
#define NB    32
#define HIDV  2560
#define HD    128
#define NQH   32
#define NKVH  8
// pool: (4096 pages, 16 slots, 8 kvh, 128 d)

typedef __bf16 bf16x8 __attribute__((ext_vector_type(8)));
typedef float  f32x4  __attribute__((ext_vector_type(4)));

__device__ __forceinline__ unsigned bfpack(float a, float b) {
  unsigned ua = __float_as_uint(a), ub = __float_as_uint(b);
  ua = (ua + 0x7FFFu + ((ua >> 16) & 1u)) >> 16;   // RNE to bf16
  ub = (ub + 0x7FFFu + ((ub >> 16) & 1u)) >> 16;
  return ua | (ub << 16);
}

// ---------------------------------------------------------------------------
// 256-thread GEMM body (R7-proven) — used by the FALLBACK kernels.
// ---------------------------------------------------------------------------
__device__ __forceinline__ void gemm_body(
    const float* __restrict__ X, const float* __restrict__ W,
    float* __restrict__ P, int N, int K, int f0, int kc0, int slabs, int t,
    unsigned short* Wl, unsigned short* Xl) {
  const int w = t >> 6, l = t & 63;
  const int rA = l & 15, kq = l >> 4;
  f32x4 acc0 = {0.f, 0.f, 0.f, 0.f}, acc1 = {0.f, 0.f, 0.f, 0.f};

  for (int s = 0; s < slabs; ++s) {
    const int kc = kc0 * slabs + s;
    if (s) __syncthreads();
    const float* Wg = W + (size_t)f0 * K + (size_t)kc * 256;
    #pragma unroll
    for (int i = 0; i < 16; ++i) {
      int idx = i * 256 + t;
      int row = idx >> 6, c4 = idx & 63;
      float4 w4 = *(const float4*)(Wg + (size_t)row * K + c4 * 4);
      *(uint2*)((char*)Wl + row * 528 + c4 * 8) =
          make_uint2(bfpack(w4.x, w4.y), bfpack(w4.z, w4.w));
    }
    const float* Xg = X + (size_t)kc * 256;
    #pragma unroll
    for (int i = 0; i < 8; ++i) {
      int idx = i * 256 + t;
      int row = idx >> 6, c4 = idx & 63;
      float4 x4 = *(const float4*)(Xg + (size_t)row * K + c4 * 4);
      *(uint2*)((char*)Xl + row * 528 + c4 * 8) =
          make_uint2(bfpack(x4.x, x4.y), bfpack(x4.z, x4.w));
    }
    __syncthreads();

    const char* pa0 = (const char*)Xl + rA * 528 + kq * 16;
    const char* pa1 = pa0 + 16 * 528;
    const char* pb  = (const char*)Wl + (w * 16 + rA) * 528 + kq * 16;
    #pragma unroll
    for (int ks = 0; ks < 8; ++ks) {
      bf16x8 a0 = *(const bf16x8*)(pa0 + ks * 64);
      bf16x8 a1 = *(const bf16x8*)(pa1 + ks * 64);
      bf16x8 bb = *(const bf16x8*)(pb  + ks * 64);
      acc0 = __builtin_amdgcn_mfma_f32_16x16x32_bf16(a0, bb, acc0, 0, 0, 0);
      acc1 = __builtin_amdgcn_mfma_f32_16x16x32_bf16(a1, bb, acc1, 0, 0, 0);
    }
  }
  const int fcol = f0 + w * 16 + rA;
  float* Pr = P + ((size_t)kc0 * 32) * N + fcol;
  #pragma unroll
  for (int j = 0; j < 4; ++j) {
    int b0 = kq * 4 + j;
    Pr[(size_t)b0 * N]        = acc0[j];
    Pr[(size_t)(b0 + 16) * N] = acc1[j];
  }
}

// ---------------------------------------------------------------------------
// 512-thread GEMM body for the fused kernel: all threads stage, waves 0-3 MFMA.
// ---------------------------------------------------------------------------
__device__ __forceinline__ void gemm512(
    const float* __restrict__ X, const float* __restrict__ W,
    float* __restrict__ P, int N, int K, int f0, int kc0, int slabs, int t,
    unsigned short* Wl, unsigned short* Xl) {
  const bool act = t < 256;
  const int w = (t >> 6) & 3, l = t & 63;
  const int rA = l & 15, kq = l >> 4;
  f32x4 acc0 = {0.f, 0.f, 0.f, 0.f}, acc1 = {0.f, 0.f, 0.f, 0.f};

  for (int s = 0; s < slabs; ++s) {
    const int kc = kc0 * slabs + s;
    if (s) __syncthreads();
    const float* Wg = W + (size_t)f0 * K + (size_t)kc * 256;
    #pragma unroll
    for (int i = 0; i < 8; ++i) {            // 64 rows x 64 f4 slots
      int idx = i * 512 + t;
      int row = idx >> 6, c4 = idx & 63;
      float4 w4 = *(const float4*)(Wg + (size_t)row * K + c4 * 4);
      *(uint2*)((char*)Wl + row * 528 + c4 * 8) =
          make_uint2(bfpack(w4.x, w4.y), bfpack(w4.z, w4.w));
    }
    const float* Xg = X + (size_t)kc * 256;
    #pragma unroll
    for (int i = 0; i < 4; ++i) {            // 32 rows x 64 f4 slots
      int idx = i * 512 + t;
      int row = idx >> 6, c4 = idx & 63;
      float4 x4 = *(const float4*)(Xg + (size_t)row * K + c4 * 4);
      *(uint2*)((char*)Xl + row * 528 + c4 * 8) =
          make_uint2(bfpack(x4.x, x4.y), bfpack(x4.z, x4.w));
    }
    __syncthreads();

    if (act) {
      const char* pa0 = (const char*)Xl + rA * 528 + kq * 16;
      const char* pa1 = pa0 + 16 * 528;
      const char* pb  = (const char*)Wl + (w * 16 + rA) * 528 + kq * 16;
      #pragma unroll
      for (int ks = 0; ks < 8; ++ks) {
        bf16x8 a0 = *(const bf16x8*)(pa0 + ks * 64);
        bf16x8 a1 = *(const bf16x8*)(pa1 + ks * 64);
        bf16x8 bb = *(const bf16x8*)(pb  + ks * 64);
        acc0 = __builtin_amdgcn_mfma_f32_16x16x32_bf16(a0, bb, acc0, 0, 0, 0);
        acc1 = __builtin_amdgcn_mfma_f32_16x16x32_bf16(a1, bb, acc1, 0, 0, 0);
      }
    }
  }
  if (act) {
    const int fcol = f0 + w * 16 + rA;
    float* Pr = P + ((size_t)kc0 * 32) * N + fcol;
    #pragma unroll
    for (int j = 0; j < 4; ++j) {
      int b0 = kq * 4 + j;
      Pr[(size_t)b0 * N]        = acc0[j];
      Pr[(size_t)(b0 + 16) * N] = acc1[j];
    }
  }
}

// ---------------------------------------------------------------------------
// FUSED cooperative kernel. grid=256 x 512 (1 block/CU guaranteed).
// P1 qkv(480u) | P2 finqkv quads(384u) | P3 attn(256u, R7 body) |
// P4 o_gemm(320u) | P5 oreduce. grid.sync() between phases.
// ---------------------------------------------------------------------------
__global__ __launch_bounds__(512, 2) void fused(
    const float* __restrict__ x, const float* __restrict__ cosb,
    const float* __restrict__ sinb, const float* __restrict__ Wq,
    const float* __restrict__ Wk, const float* __restrict__ Wv,
    const float* __restrict__ Wo, const float* __restrict__ qw,
    const float* __restrict__ kw, const float* __restrict__ Kp,
    const float* __restrict__ Vp, const int* __restrict__ pidx,
    const int* __restrict__ lens, float* __restrict__ qp,
    float* __restrict__ kp, float* __restrict__ vp, float* __restrict__ qn,
    float* __restrict__ kn, float* __restrict__ vn, float* __restrict__ ao,
    float* __restrict__ op, float* __restrict__ y) {
  cg::grid_group grid = cg::this_grid();
  __shared__ __align__(16) char smem[67072];   // gemm 50688 / attn 67072
  const int bid = blockIdx.x, t = threadIdx.x;

  // ---- P1: QKV projection, 480 units = (96 bx, 5 kc) ----
  for (int u = bid; u < 480; u += 256) {
    __syncthreads();                           // LDS reuse guard across units
    unsigned short* Wl = (unsigned short*)smem;
    unsigned short* Xl = (unsigned short*)(smem + 33792);
    const int bx = u / 5, kc = u - bx * 5;
    const float* W; float* P; int N, f0;
    if (bx < 64)      { W = Wq; P = qp; N = 4096; f0 = bx * 64; }
    else if (bx < 80) { W = Wk; P = kp; N = 1024; f0 = (bx - 64) * 64; }
    else              { W = Wv; P = vp; N = 1024; f0 = (bx - 80) * 64; }
    gemm512(x, W, P, N, 2560, f0, kc, 2, t, Wl, Xl);
  }
  grid.sync();

  // ---- P2: reduce 5 partials + RMSNorm + RoPE, 384 quad-units ----
  {
    float* red = (float*)smem;               // [8]
    float* sh  = (float*)(smem + 32);        // [4][128]
    for (int u = bid; u < 384; u += 256) {
      const int b = u / 12, qd = u - (u / 12) * 12;
      const int hl = t >> 7, d = t & 127;    // head-in-quad, dim
      const int H = qd * 4 + hl;             // 0..31 q, 32..39 k, 40..47 v
      __syncthreads();                       // red/sh reuse guard
      if (qd >= 10) {                        // v quad: partial-sum copy
        float xv = 0.f;
        #pragma unroll
        for (int c = 0; c < 5; ++c)
          xv += vp[(size_t)(c * 32 + b) * 1024 + (H - 40) * 128 + d];
        vn[((size_t)b * 8 + (H - 40)) * 128 + d] = xv;
      } else {
        const bool isq = qd < 8;
        float xx = 0.f;
        if (isq) {
          #pragma unroll
          for (int c = 0; c < 5; ++c)
            xx += qp[(size_t)(c * 32 + b) * 4096 + H * 128 + d];
        } else {
          #pragma unroll
          for (int c = 0; c < 5; ++c)
            xx += kp[(size_t)(c * 32 + b) * 1024 + (H - 32) * 128 + d];
        }
        float ss = xx * xx;
        #pragma unroll
        for (int mk = 1; mk < 64; mk <<= 1) ss += __shfl_xor(ss, mk);
        if ((t & 63) == 0) red[t >> 6] = ss;
        __syncthreads();
        const float inv =
            rsqrtf((red[hl * 2] + red[hl * 2 + 1]) * (1.f / 128.f) + 1e-6f);
        const float xn = xx * inv * (isq ? qw[d] : kw[d]);
        sh[hl * 128 + d] = xn;
        __syncthreads();
        const float rp = sh[hl * 128 + (d ^ 64)];
        const float o = xn * cosb[b * 128 + d] +
                        ((d < 64) ? -rp : rp) * sinb[b * 128 + d];
        if (isq) qn[((size_t)b * 32 + H) * 128 + d] = o;
        else     kn[((size_t)b * 8 + (H - 32)) * 128 + d] = o;
      }
    }
  }
  grid.sync();

  // ---- P3: attention, one (b,kvh) per block — R7 body verbatim ----
  {
    int* pages = (int*)smem;                              // [128]
    float (*mmS)[4] = (float(*)[4])(smem + 512);          // [32][4]
    float (*msS)[4] = (float(*)[4])(smem + 1024);         // [32][4]
    float (*maccS)[4][128] = (float(*)[4][128])(smem + 1536); // [32][4][128]
    const int b = bid >> 3, kvh = bid & 7;
    const int w = t >> 6, l = t & 63;
    const int sub = l >> 4, di = (l & 15) * 8;
    if (t < 128) pages[t] = pidx[b * 128 + t];
    __syncthreads();
    const int len = lens[b], lim = len - 1;   // pool tokens: [0, lim)

    float qf[4][8];
    const float SC = 0.08838834764831845f * 1.4426950408889634f;
    #pragma unroll
    for (int g = 0; g < 4; ++g)
      #pragma unroll
      for (int j = 0; j < 8; ++j)
        qf[g][j] = qn[((size_t)b * 32 + kvh * 4 + g) * 128 + di + j] * SC;

    float m[4], se[4], acc[4][8];
    #pragma unroll
    for (int g = 0; g < 4; ++g) {
      m[g] = -INFINITY; se[g] = 0.f;
      #pragma unroll
      for (int j = 0; j < 8; ++j) acc[g][j] = 0.f;
    }

    const int t0 = w * 4 + sub;
    const int nit = (lim + 31) >> 5;

    auto update = [&](const float (&ck)[8], const float (&cv)[8], bool valid) {
      float s[4];
      #pragma unroll
      for (int g = 0; g < 4; ++g) {
        float d8 = 0.f;
        #pragma unroll
        for (int j = 0; j < 8; ++j) d8 += qf[g][j] * ck[j];
        s[g] = d8;
      }
      #pragma unroll
      for (int mk = 1; mk < 16; mk <<= 1) {
        #pragma unroll
        for (int g = 0; g < 4; ++g) s[g] += __shfl_xor(s[g], mk);
      }
      if (valid) {
        #pragma unroll
        for (int g = 0; g < 4; ++g) {
          const float sg = s[g];
          if (sg > m[g]) {
            const float scf = exp2f(m[g] - sg);
            m[g] = sg;
            se[g] = se[g] * scf + 1.f;
            #pragma unroll
            for (int j = 0; j < 8; ++j) acc[g][j] = acc[g][j] * scf + cv[j];
          } else {
            const float p = exp2f(sg - m[g]);
            se[g] += p;
            #pragma unroll
            for (int j = 0; j < 8; ++j) acc[g][j] += p * cv[j];
          }
        }
      }
    };

    f32x4 ka0, ka1, va0, va1, kb0, kb1, vb0, vb1;
    {
      int tt = min(t0, lim - 1);
      size_t a = ((size_t)pages[tt >> 4] * 16 + (tt & 15)) * 1024 + kvh * 128 + di;
      ka0 = *(const f32x4*)(Kp + a); ka1 = *(const f32x4*)(Kp + a + 4);
      va0 = *(const f32x4*)(Vp + a); va1 = *(const f32x4*)(Vp + a + 4);
    }
    if (nit > 1) {
      int tt = min(32 + t0, lim - 1);
      size_t a = ((size_t)pages[tt >> 4] * 16 + (tt & 15)) * 1024 + kvh * 128 + di;
      kb0 = *(const f32x4*)(Kp + a); kb1 = *(const f32x4*)(Kp + a + 4);
      vb0 = *(const f32x4*)(Vp + a); vb1 = *(const f32x4*)(Vp + a + 4);
    }
    for (int it = 0; it < nit; it += 2) {
      {
        const float ck[8] = {ka0[0], ka0[1], ka0[2], ka0[3], ka1[0], ka1[1], ka1[2], ka1[3]};
        const float cv[8] = {va0[0], va0[1], va0[2], va0[3], va1[0], va1[1], va1[2], va1[3]};
        if (it + 2 < nit) {
          int tt = min((it + 2) * 32 + t0, lim - 1);
          size_t a = ((size_t)pages[tt >> 4] * 16 + (tt & 15)) * 1024 + kvh * 128 + di;
          ka0 = *(const f32x4*)(Kp + a); ka1 = *(const f32x4*)(Kp + a + 4);
          va0 = *(const f32x4*)(Vp + a); va1 = *(const f32x4*)(Vp + a + 4);
        }
        update(ck, cv, it * 32 + t0 < lim);
      }
      if (it + 1 < nit) {
        const float ck[8] = {kb0[0], kb0[1], kb0[2], kb0[3], kb1[0], kb1[1], kb1[2], kb1[3]};
        const float cv[8] = {vb0[0], vb0[1], vb0[2], vb0[3], vb1[0], vb1[1], vb1[2], vb1[3]};
        if (it + 3 < nit) {
          int tt = min((it + 3) * 32 + t0, lim - 1);
          size_t a = ((size_t)pages[tt >> 4] * 16 + (tt & 15)) * 1024 + kvh * 128 + di;
          kb0 = *(const f32x4*)(Kp + a); kb1 = *(const f32x4*)(Kp + a + 4);
          vb0 = *(const f32x4*)(Vp + a); vb1 = *(const f32x4*)(Vp + a + 4);
        }
        update(ck, cv, (it + 1) * 32 + t0 < lim);
      }
    }

    if (w == 0) {                            // new decode token
      const float* kr = kn + ((size_t)b * 8 + kvh) * 128 + di;
      const float* vr = vn + ((size_t)b * 8 + kvh) * 128 + di;
      float ck[8], cv[8];
      #pragma unroll
      for (int j = 0; j < 8; ++j) { ck[j] = kr[j]; cv[j] = vr[j]; }
      update(ck, cv, sub == 0);
    }

    const int st = w * 4 + sub;
    if ((l & 15) == 0) {
      #pragma unroll
      for (int g = 0; g < 4; ++g) { mmS[st][g] = m[g]; msS[st][g] = se[g]; }
    }
    #pragma unroll
    for (int g = 0; g < 4; ++g)
      #pragma unroll
      for (int j = 0; j < 8; ++j) maccS[st][g][di + j] = acc[g][j];
    __syncthreads();

    const int g = t >> 7, dd = t & 127;
    float M = -INFINITY;
    #pragma unroll
    for (int s2 = 0; s2 < 32; ++s2) M = fmaxf(M, mmS[s2][g]);
    float den = 0.f, num = 0.f;
    for (int s2 = 0; s2 < 32; ++s2) {
      const float wg = exp2f(mmS[s2][g] - M);
      den += wg * msS[s2][g];
      num += wg * maccS[s2][g][dd];
    }
    ao[((size_t)b * 32 + kvh * 4 + g) * 128 + dd] = num / den;
  }
  grid.sync();

  // ---- P4: o_proj GEMM, 320 units = (40 bx, 8 kc) ----
  for (int u = bid; u < 320; u += 256) {
    __syncthreads();
    unsigned short* Wl = (unsigned short*)smem;
    unsigned short* Xl = (unsigned short*)(smem + 33792);
    gemm512(ao, Wo, op, 2560, 4096, (u >> 3) * 64, u & 7, 2, t, Wl, Xl);
  }
  grid.sync();

  // ---- P5: o_proj partial reduce (81920 outs, single pass) ----
  {
    const int i = bid * 512 + t;
    if (i < 81920) {
      float s = 0.f;
      #pragma unroll
      for (int c = 0; c < 8; ++c) s += op[(size_t)c * 81920 + i];
      y[i] = s;
    }
  }
}

// ===================== FALLBACK: R7-proven 5-kernel path =====================
__global__ __launch_bounds__(256) void qkv_gemm(
    const float* __restrict__ X, const float* __restrict__ Wq,
    const float* __restrict__ Wk, const float* __restrict__ Wv,
    float* __restrict__ qp, float* __restrict__ kp, float* __restrict__ vp) {
  __shared__ __align__(16) unsigned short Wl[64 * 264];
  __shared__ __align__(16) unsigned short Xl[32 * 264];
  const int bx = blockIdx.x;
  const float* W; float* P; int N, f0;
  if (bx < 64)      { W = Wq; P = qp; N = 4096; f0 = bx * 64; }
  else if (bx < 80) { W = Wk; P = kp; N = 1024; f0 = (bx - 64) * 64; }
  else              { W = Wv; P = vp; N = 1024; f0 = (bx - 80) * 64; }
  gemm_body(X, W, P, N, 2560, f0, blockIdx.y, 2, threadIdx.x, Wl, Xl);
}

__global__ __launch_bounds__(256) void o_gemm(
    const float* __restrict__ X, const float* __restrict__ W,
    float* __restrict__ P) {
  __shared__ __align__(16) unsigned short Wl[64 * 264];
  __shared__ __align__(16) unsigned short Xl[32 * 264];
  gemm_body(X, W, P, 2560, 4096, blockIdx.x * 64, blockIdx.y, 2, threadIdx.x, Wl, Xl);
}

__global__ __launch_bounds__(128) void finqkv(
    const float* __restrict__ qp, const float* __restrict__ kp,
    const float* __restrict__ vp, const float* __restrict__ cosb,
    const float* __restrict__ sinb, const float* __restrict__ qw,
    const float* __restrict__ kw, float* __restrict__ qn,
    float* __restrict__ kn, float* __restrict__ vn) {
  const int b = blockIdx.x, h = blockIdx.y, d = threadIdx.x;
  float x = 0.f;
  if (h < 32) {
    #pragma unroll
    for (int c = 0; c < 5; ++c) x += qp[(size_t)(c * 32 + b) * 4096 + h * 128 + d];
  } else if (h < 40) {
    #pragma unroll
    for (int c = 0; c < 5; ++c) x += kp[(size_t)(c * 32 + b) * 1024 + (h - 32) * 128 + d];
  } else {
    #pragma unroll
    for (int c = 0; c < 5; ++c) x += vp[(size_t)(c * 32 + b) * 1024 + (h - 40) * 128 + d];
  }
  if (h >= 40) { vn[((size_t)b * 8 + (h - 40)) * 128 + d] = x; return; }

  __shared__ float red[2];
  __shared__ float sh[128];
  float ss = x * x;
  #pragma unroll
  for (int mk = 1; mk < 64; mk <<= 1) ss += __shfl_xor(ss, mk);
  if ((d & 63) == 0) red[d >> 6] = ss;
  __syncthreads();
  const float inv = rsqrtf((red[0] + red[1]) * (1.f / 128.f) + 1e-6f);
  const float* nw = (h < 32) ? qw : kw;
  const float xn = x * inv * nw[d];
  sh[d] = xn;
  __syncthreads();
  const float rot = (d < 64) ? -sh[d + 64] : sh[d - 64];
  const float o = xn * cosb[b * 128 + d] + rot * sinb[b * 128 + d];
  if (h < 32) qn[((size_t)b * 32 + h) * 128 + d] = o;
  else        kn[((size_t)b * 8 + (h - 32)) * 128 + d] = o;
}

__global__ __launch_bounds__(512) void attn(
    const float* __restrict__ Kp, const float* __restrict__ Vp,
    const float* __restrict__ qn, const float* __restrict__ kn,
    const float* __restrict__ vn, const int* __restrict__ pidx,
    const int* __restrict__ lens, float* __restrict__ ao) {
  const int b = blockIdx.x >> 3, kvh = blockIdx.x & 7;
  const int t = threadIdx.x, w = t >> 6, l = t & 63;
  const int sub = l >> 4, di = (l & 15) * 8;
  __shared__ int pages[128];
  __shared__ float mmS[32][4], msS[32][4];
  __shared__ __align__(16) float maccS[32][4][128];
  if (t < 128) pages[t] = pidx[b * 128 + t];
  __syncthreads();
  const int len = lens[b], lim = len - 1;

  float qf[4][8];
  const float SC = 0.08838834764831845f * 1.4426950408889634f;
  #pragma unroll
  for (int g = 0; g < 4; ++g)
    #pragma unroll
    for (int j = 0; j < 8; ++j)
      qf[g][j] = qn[((size_t)b * 32 + kvh * 4 + g) * 128 + di + j] * SC;

  float m[4], se[4], acc[4][8];
  #pragma unroll
  for (int g = 0; g < 4; ++g) {
    m[g] = -INFINITY; se[g] = 0.f;
    #pragma unroll
    for (int j = 0; j < 8; ++j) acc[g][j] = 0.f;
  }

  const int t0 = w * 4 + sub;
  const int nit = (lim + 31) >> 5;

  auto update = [&](const float (&ck)[8], const float (&cv)[8], bool valid) {
    float s[4];
    #pragma unroll
    for (int g = 0; g < 4; ++g) {
      float d8 = 0.f;
      #pragma unroll
      for (int j = 0; j < 8; ++j) d8 += qf[g][j] * ck[j];
      s[g] = d8;
    }
    #pragma unroll
    for (int mk = 1; mk < 16; mk <<= 1) {
      #pragma unroll
      for (int g = 0; g < 4; ++g) s[g] += __shfl_xor(s[g], mk);
    }
    if (valid) {
      #pragma unroll
      for (int g = 0; g < 4; ++g) {
        const float sg = s[g];
        if (sg > m[g]) {
          const float scf = exp2f(m[g] - sg);
          m[g] = sg;
          se[g] = se[g] * scf + 1.f;
          #pragma unroll
          for (int j = 0; j < 8; ++j) acc[g][j] = acc[g][j] * scf + cv[j];
        } else {
          const float p = exp2f(sg - m[g]);
          se[g] += p;
          #pragma unroll
          for (int j = 0; j < 8; ++j) acc[g][j] += p * cv[j];
        }
      }
    }
  };

  f32x4 ka0, ka1, va0, va1, kb0, kb1, vb0, vb1;
  {
    int tt = min(t0, lim - 1);
    size_t a = ((size_t)pages[tt >> 4] * 16 + (tt & 15)) * 1024 + kvh * 128 + di;
    ka0 = *(const f32x4*)(Kp + a); ka1 = *(const f32x4*)(Kp + a + 4);
    va0 = *(const f32x4*)(Vp + a); va1 = *(const f32x4*)(Vp + a + 4);
  }
  if (nit > 1) {
    int tt = min(32 + t0, lim - 1);
    size_t a = ((size_t)pages[tt >> 4] * 16 + (tt & 15)) * 1024 + kvh * 128 + di;
    kb0 = *(const f32x4*)(Kp + a); kb1 = *(const f32x4*)(Kp + a + 4);
    vb0 = *(const f32x4*)(Vp + a); vb1 = *(const f32x4*)(Vp + a + 4);
  }
  for (int it = 0; it < nit; it += 2) {
    {
      const float ck[8] = {ka0[0], ka0[1], ka0[2], ka0[3], ka1[0], ka1[1], ka1[2], ka1[3]};
      const float cv[8] = {va0[0], va0[1], va0[2], va0[3], va1[0], va1[1], va1[2], va1[3]};
      if (it + 2 < nit) {
        int tt = min((it + 2) * 32 + t0, lim - 1);
        size_t a = ((size_t)pages[tt >> 4] * 16 + (tt & 15)) * 1024 + kvh * 128 + di;
        ka0 = *(const f32x4*)(Kp + a); ka1 = *(const f32x4*)(Kp + a + 4);
        va0 = *(const f32x4*)(Vp + a); va1 = *(const f32x4*)(Vp + a + 4);
      }
      update(ck, cv, it * 32 + t0 < lim);
    }
    if (it + 1 < nit) {
      const float ck[8] = {kb0[0], kb0[1], kb0[2], kb0[3], kb1[0], kb1[1], kb1[2], kb1[3]};
      const float cv[8] = {vb0[0], vb0[1], vb0[2], vb0[3], vb1[0], vb1[1], vb1[2], vb1[3]};
      if (it + 3 < nit) {
        int tt = min((it + 3) * 32 + t0, lim - 1);
        size_t a = ((size_t)pages[tt >> 4] * 16 + (tt & 15)) * 1024 + kvh * 128 + di;
        kb0 = *(const f32x4*)(Kp + a); kb1 = *(const f32x4*)(Kp + a + 4);
        vb0 = *(const f32x4*)(Vp + a); vb1 = *(const f32x4*)(Vp + a + 4);
      }
      update(ck, cv, (it + 1) * 32 + t0 < lim);
    }
  }

  if (w == 0) {
    const float* kr = kn + ((size_t)b * 8 + kvh) * 128 + di;
    const float* vr = vn + ((size_t)b * 8 + kvh) * 128 + di;
    float ck[8], cv[8];
    #pragma unroll
    for (int j = 0; j < 8; ++j) { ck[j] = kr[j]; cv[j] = vr[j]; }
    update(ck, cv, sub == 0);
  }

  const int st = w * 4 + sub;
  if ((l & 15) == 0) {
    #pragma unroll
    for (int g = 0; g < 4; ++g) { mmS[st][g] = m[g]; msS[st][g] = se[g]; }
  }
  #pragma unroll
  for (int g = 0; g < 4; ++g)
    #pragma unroll
    for (int j = 0; j < 8; ++j) maccS[st][g][di + j] = acc[g][j];
  __syncthreads();

  const int g = t >> 7, dd = t & 127;
  float M = -INFINITY;
  #pragma unroll
  for (int s2 = 0; s2 < 32; ++s2) M = fmaxf(M, mmS[s2][g]);
  float den = 0.f, num = 0.f;
  for (int s2 = 0; s2 < 32; ++s2) {
    const float wg = exp2f(mmS[s2][g] - M);
    den += wg * msS[s2][g];
    num += wg * maccS[s2][g][dd];
  }
  ao[((size_t)b * 32 + kvh * 4 + g) * 128 + dd] = num / den;
}

__global__ __launch_bounds__(256) void oreduce(const float* __restrict__ op,
                                               float* __restrict__ y) {
  const int i = blockIdx.x * 256 + threadIdx.x;
  float s = 0.f;
  #pragma unroll
  for (int c = 0; c < 8; ++c) s += op[(size_t)c * (32 * 2560) + i];
  y[i] = s;
}

// ---------------------------------------------------------------------------
extern "C" void kernel_launch(void* const* d_in, const int* in_sizes, int n_in,
                              void* d_out, int out_size, void* d_ws, size_t ws_size,
                              hipStream_t stream) {
  const float* x    = (const float*)d_in[0];
  const float* cosb = (const float*)d_in[1];
  const float* sinb = (const float*)d_in[2];
  const float* Wq   = (const float*)d_in[3];
  const float* Wk   = (const float*)d_in[4];
  const float* Wv   = (const float*)d_in[5];
  const float* Wo   = (const float*)d_in[6];
  const float* qw   = (const float*)d_in[7];
  const float* kw   = (const float*)d_in[8];
  const float* Kp   = (const float*)d_in[9];
  const float* Vp   = (const float*)d_in[10];
  const int*   pidx = (const int*)d_in[11];
  const int*   lens = (const int*)d_in[12];
  float* y = (float*)d_out;

  float* ws = (float*)d_ws;
  float* qp = ws;                     // [5][32][4096] (op alias: [8][32][2560])
  float* kp = qp + 655360;            // [5][32][1024]
  float* vp = kp + 163840;            // [5][32][1024]
  float* qn = vp + 163840;            // [32][32][128]
  float* kn = qn + 131072;            // [32][8][128]
  float* vn = kn + 32768;             // [32][8][128]
  float* ao = vn + 32768;             // [32][32*128]
  float* op = qp;                     // reuse
  (void)in_sizes; (void)n_in; (void)out_size; (void)ws_size;

  void* args[] = {&x, &cosb, &sinb, &Wq, &Wk, &Wv, &Wo, &qw, &kw, &Kp, &Vp,
                  &pidx, &lens, &qp, &kp, &vp, &qn, &kn, &vn, &ao, &op, &y};
  hipError_t e = hipLaunchCooperativeKernel((void*)fused, dim3(256), dim3(512),
                                            args, 0, stream);
  if (e != hipSuccess) {
    (void)hipGetLastError();                 // clear error state
    // R7-proven fallback path
    qkv_gemm<<<dim3(96, 5), 256, 0, stream>>>(x, Wq, Wk, Wv, qp, kp, vp);
    finqkv<<<dim3(32, 48), 128, 0, stream>>>(qp, kp, vp, cosb, sinb, qw, kw, qn, kn, vn);
    attn<<<256, 512, 0, stream>>>(Kp, Vp, qn, kn, vn, pidx, lens, ao);
    o_gemm<<<dim3(40, 8), 256, 0, stream>>>(ao, Wo, op);
    oreduce<<<320, 256, 0, stream>>>(op, y);
  }
}

// Round 12
// 213.624 us; speedup vs baseline: 1.0671x; 1.0671x over previous
//
#include <hip/hip_runtime.h>
#include <math.h>

// Problem constants (Qwen3-4B-like decode)
#define NB    32
#define HIDV  2560
#define HD    128
#define NQH   32
#define NKVH  8
// pool: (4096 pages, 16 slots, 8 kvh, 128 d)

typedef __bf16 bf16x8 __attribute__((ext_vector_type(8)));
typedef float  f32x4  __attribute__((ext_vector_type(4)));

__device__ __forceinline__ unsigned bfpack(float a, float b) {
  unsigned ua = __float_as_uint(a), ub = __float_as_uint(b);
  ua = (ua + 0x7FFFu + ((ua >> 16) & 1u)) >> 16;   // RNE to bf16
  ub = (ub + 0x7FFFu + ((ub >> 16) & 1u)) >> 16;
  return ua | (ub << 16);
}

// ---------------------------------------------------------------------------
// Partial GEMM body (R7-proven): P[kc0][b][f] = 2 slabs of 256 K each.
// ---------------------------------------------------------------------------
__device__ __forceinline__ void gemm_body(
    const float* __restrict__ X, const float* __restrict__ W,
    float* __restrict__ P, int N, int K, int f0, int kc0, int slabs, int t,
    unsigned short* Wl, unsigned short* Xl) {
  const int w = t >> 6, l = t & 63;
  const int rA = l & 15, kq = l >> 4;
  f32x4 acc0 = {0.f, 0.f, 0.f, 0.f}, acc1 = {0.f, 0.f, 0.f, 0.f};

  for (int s = 0; s < slabs; ++s) {
    const int kc = kc0 * slabs + s;
    if (s) __syncthreads();
    const float* Wg = W + (size_t)f0 * K + (size_t)kc * 256;
    #pragma unroll
    for (int i = 0; i < 16; ++i) {
      int idx = i * 256 + t;
      int row = idx >> 6, c4 = idx & 63;
      float4 w4 = *(const float4*)(Wg + (size_t)row * K + c4 * 4);
      *(uint2*)((char*)Wl + row * 528 + c4 * 8) =
          make_uint2(bfpack(w4.x, w4.y), bfpack(w4.z, w4.w));
    }
    const float* Xg = X + (size_t)kc * 256;
    #pragma unroll
    for (int i = 0; i < 8; ++i) {
      int idx = i * 256 + t;
      int row = idx >> 6, c4 = idx & 63;
      float4 x4 = *(const float4*)(Xg + (size_t)row * K + c4 * 4);
      *(uint2*)((char*)Xl + row * 528 + c4 * 8) =
          make_uint2(bfpack(x4.x, x4.y), bfpack(x4.z, x4.w));
    }
    __syncthreads();

    const char* pa0 = (const char*)Xl + rA * 528 + kq * 16;
    const char* pa1 = pa0 + 16 * 528;
    const char* pb  = (const char*)Wl + (w * 16 + rA) * 528 + kq * 16;
    #pragma unroll
    for (int ks = 0; ks < 8; ++ks) {
      bf16x8 a0 = *(const bf16x8*)(pa0 + ks * 64);
      bf16x8 a1 = *(const bf16x8*)(pa1 + ks * 64);
      bf16x8 bb = *(const bf16x8*)(pb  + ks * 64);
      acc0 = __builtin_amdgcn_mfma_f32_16x16x32_bf16(a0, bb, acc0, 0, 0, 0);
      acc1 = __builtin_amdgcn_mfma_f32_16x16x32_bf16(a1, bb, acc1, 0, 0, 0);
    }
  }
  const int fcol = f0 + w * 16 + rA;   // C/D: col=lane&15, row=(lane>>4)*4+j
  float* Pr = P + ((size_t)kc0 * 32) * N + fcol;
  #pragma unroll
  for (int j = 0; j < 4; ++j) {
    int b0 = kq * 4 + j;
    Pr[(size_t)b0 * N]        = acc0[j];
    Pr[(size_t)(b0 + 16) * N] = acc1[j];
  }
}

// ---------------------------------------------------------------------------
// QKV projection with fused finqkv epilogue (last-block-done).
// grid (96, 5), block 256. Counter id: q head (bx>>1), 32+k head, 40+v head;
// each counter reaches 10 (2 bx-halves x 5 kc). Winner reduces 5 partials,
// RMSNorm + RoPE for its head across all 32 batches.
// ---------------------------------------------------------------------------
__global__ __launch_bounds__(256) void qkv_gemm_f(
    const float* __restrict__ X, const float* __restrict__ Wq,
    const float* __restrict__ Wk, const float* __restrict__ Wv,
    const float* __restrict__ cosb, const float* __restrict__ sinb,
    const float* __restrict__ qw, const float* __restrict__ kw,
    float* __restrict__ qp, float* __restrict__ kp, float* __restrict__ vp,
    float* __restrict__ qn, float* __restrict__ kn, float* __restrict__ vn,
    int* __restrict__ cnt) {
  __shared__ __align__(16) unsigned short Wl[64 * 264];
  __shared__ __align__(16) unsigned short Xl[32 * 264];
  __shared__ int oldv;
  __shared__ float red2[4];
  __shared__ float sh2[2][128];
  const int bx = blockIdx.x, t = threadIdx.x;
  const float* W; float* P; int N, f0;
  if (bx < 64)      { W = Wq; P = qp; N = 4096; f0 = bx * 64; }
  else if (bx < 80) { W = Wk; P = kp; N = 1024; f0 = (bx - 64) * 64; }
  else              { W = Wv; P = vp; N = 1024; f0 = (bx - 80) * 64; }
  gemm_body(X, W, P, N, 2560, f0, blockIdx.y, 2, t, Wl, Xl);

  // ---- last-block-done election ----
  const int id = (bx < 64) ? (bx >> 1)
               : (bx < 80) ? 32 + ((bx - 64) >> 1)
                           : 40 + ((bx - 80) >> 1);
  __threadfence();                    // release this block's partial stores
  __syncthreads();
  if (t == 0) oldv = atomicAdd(&cnt[id], 1);
  __syncthreads();
  if (oldv != 9) return;
  __threadfence();                    // acquire other blocks' stores

  // ---- epilogue: one head (128 dims) x 32 batches, 2 rows per pass ----
  const int r = t >> 7, d = t & 127;
  if (id >= 40) {                     // v head: plain 5-chunk sum
    const int h = id - 40;
    #pragma unroll
    for (int i = 0; i < 16; ++i) {
      const int b = i * 2 + r;
      float xv = 0.f;
      #pragma unroll
      for (int c = 0; c < 5; ++c)
        xv += vp[(size_t)(c * 32 + b) * 1024 + h * 128 + d];
      vn[((size_t)b * 8 + h) * 128 + d] = xv;
    }
    return;
  }
  const bool isq = id < 32;
  const int h = isq ? id : id - 32;
  const float* src = isq ? qp : kp;
  const float* nw  = isq ? qw : kw;
  const int stride = isq ? 4096 : 1024;
  for (int i = 0; i < 16; ++i) {
    const int b = i * 2 + r;
    float xx = 0.f;
    #pragma unroll
    for (int c = 0; c < 5; ++c)
      xx += src[(size_t)(c * 32 + b) * stride + h * 128 + d];
    float ss = xx * xx;
    #pragma unroll
    for (int mk = 1; mk < 64; mk <<= 1) ss += __shfl_xor(ss, mk);
    if ((t & 63) == 0) red2[t >> 6] = ss;
    __syncthreads();
    const float inv = rsqrtf((red2[r * 2] + red2[r * 2 + 1]) * (1.f / 128.f) + 1e-6f);
    const float xn = xx * inv * nw[d];
    sh2[r][d] = xn;
    __syncthreads();
    const float rp = sh2[r][d ^ 64];
    const float o = xn * cosb[b * 128 + d] + ((d < 64) ? -rp : rp) * sinb[b * 128 + d];
    if (isq) qn[((size_t)b * 32 + h) * 128 + d] = o;
    else     kn[((size_t)b * 8 + h) * 128 + d] = o;
    __syncthreads();                  // red2/sh2 reuse guard
  }
}

// ---------------------------------------------------------------------------
// o_proj GEMM with fused reduce epilogue. grid (40, 8), counter to 8 per bx.
// Winner sums the 8 partials for its 64-feature column block into y.
// ---------------------------------------------------------------------------
__global__ __launch_bounds__(256) void o_gemm_f(
    const float* __restrict__ X, const float* __restrict__ W,
    float* __restrict__ op, float* __restrict__ y, int* __restrict__ cnt) {
  __shared__ __align__(16) unsigned short Wl[64 * 264];
  __shared__ __align__(16) unsigned short Xl[32 * 264];
  __shared__ int oldv;
  const int bx = blockIdx.x, t = threadIdx.x;
  const int f0 = bx * 64;
  gemm_body(X, W, op, 2560, 4096, f0, blockIdx.y, 2, t, Wl, Xl);

  __threadfence();
  __syncthreads();
  if (t == 0) oldv = atomicAdd(&cnt[48 + bx], 1);
  __syncthreads();
  if (oldv != 7) return;
  __threadfence();

  #pragma unroll
  for (int i = 0; i < 8; ++i) {       // 32 b x 64 f = 2048 outputs
    const int o = i * 256 + t, b = o >> 6, f = o & 63;
    float s = 0.f;
    #pragma unroll
    for (int c = 0; c < 8; ++c)
      s += op[(size_t)(c * 32 + b) * 2560 + f0 + f];
    y[b * 2560 + f0 + f] = s;
  }
}

// ---------------------------------------------------------------------------
// Paged GQA decode attention (R7-proven, verbatim).
// grid = 256 (b*8+kvh), block = 512 (8 waves = 32 subgroups of 16 lanes).
// ---------------------------------------------------------------------------
__global__ __launch_bounds__(512) void attn(
    const float* __restrict__ Kp, const float* __restrict__ Vp,
    const float* __restrict__ qn, const float* __restrict__ kn,
    const float* __restrict__ vn, const int* __restrict__ pidx,
    const int* __restrict__ lens, float* __restrict__ ao) {
  const int b = blockIdx.x >> 3, kvh = blockIdx.x & 7;
  const int t = threadIdx.x, w = t >> 6, l = t & 63;
  const int sub = l >> 4, di = (l & 15) * 8;
  __shared__ int pages[128];
  __shared__ float mmS[32][4], msS[32][4];
  __shared__ __align__(16) float maccS[32][4][128];
  if (t < 128) pages[t] = pidx[b * 128 + t];
  __syncthreads();
  const int len = lens[b], lim = len - 1;

  float qf[4][8];
  const float SC = 0.08838834764831845f * 1.4426950408889634f;
  #pragma unroll
  for (int g = 0; g < 4; ++g)
    #pragma unroll
    for (int j = 0; j < 8; ++j)
      qf[g][j] = qn[((size_t)b * 32 + kvh * 4 + g) * 128 + di + j] * SC;

  float m[4], se[4], acc[4][8];
  #pragma unroll
  for (int g = 0; g < 4; ++g) {
    m[g] = -INFINITY; se[g] = 0.f;
    #pragma unroll
    for (int j = 0; j < 8; ++j) acc[g][j] = 0.f;
  }

  const int t0 = w * 4 + sub;
  const int nit = (lim + 31) >> 5;

  auto update = [&](const float (&ck)[8], const float (&cv)[8], bool valid) {
    float s[4];
    #pragma unroll
    for (int g = 0; g < 4; ++g) {
      float d8 = 0.f;
      #pragma unroll
      for (int j = 0; j < 8; ++j) d8 += qf[g][j] * ck[j];
      s[g] = d8;
    }
    #pragma unroll
    for (int mk = 1; mk < 16; mk <<= 1) {
      #pragma unroll
      for (int g = 0; g < 4; ++g) s[g] += __shfl_xor(s[g], mk);
    }
    if (valid) {
      #pragma unroll
      for (int g = 0; g < 4; ++g) {
        const float sg = s[g];
        if (sg > m[g]) {
          const float scf = exp2f(m[g] - sg);
          m[g] = sg;
          se[g] = se[g] * scf + 1.f;
          #pragma unroll
          for (int j = 0; j < 8; ++j) acc[g][j] = acc[g][j] * scf + cv[j];
        } else {
          const float p = exp2f(sg - m[g]);
          se[g] += p;
          #pragma unroll
          for (int j = 0; j < 8; ++j) acc[g][j] += p * cv[j];
        }
      }
    }
  };

  f32x4 ka0, ka1, va0, va1, kb0, kb1, vb0, vb1;
  {
    int tt = min(t0, lim - 1);
    size_t a = ((size_t)pages[tt >> 4] * 16 + (tt & 15)) * 1024 + kvh * 128 + di;
    ka0 = *(const f32x4*)(Kp + a); ka1 = *(const f32x4*)(Kp + a + 4);
    va0 = *(const f32x4*)(Vp + a); va1 = *(const f32x4*)(Vp + a + 4);
  }
  if (nit > 1) {
    int tt = min(32 + t0, lim - 1);
    size_t a = ((size_t)pages[tt >> 4] * 16 + (tt & 15)) * 1024 + kvh * 128 + di;
    kb0 = *(const f32x4*)(Kp + a); kb1 = *(const f32x4*)(Kp + a + 4);
    vb0 = *(const f32x4*)(Vp + a); vb1 = *(const f32x4*)(Vp + a + 4);
  }
  for (int it = 0; it < nit; it += 2) {
    {
      const float ck[8] = {ka0[0], ka0[1], ka0[2], ka0[3], ka1[0], ka1[1], ka1[2], ka1[3]};
      const float cv[8] = {va0[0], va0[1], va0[2], va0[3], va1[0], va1[1], va1[2], va1[3]};
      if (it + 2 < nit) {
        int tt = min((it + 2) * 32 + t0, lim - 1);
        size_t a = ((size_t)pages[tt >> 4] * 16 + (tt & 15)) * 1024 + kvh * 128 + di;
        ka0 = *(const f32x4*)(Kp + a); ka1 = *(const f32x4*)(Kp + a + 4);
        va0 = *(const f32x4*)(Vp + a); va1 = *(const f32x4*)(Vp + a + 4);
      }
      update(ck, cv, it * 32 + t0 < lim);
    }
    if (it + 1 < nit) {
      const float ck[8] = {kb0[0], kb0[1], kb0[2], kb0[3], kb1[0], kb1[1], kb1[2], kb1[3]};
      const float cv[8] = {vb0[0], vb0[1], vb0[2], vb0[3], vb1[0], vb1[1], vb1[2], vb1[3]};
      if (it + 3 < nit) {
        int tt = min((it + 3) * 32 + t0, lim - 1);
        size_t a = ((size_t)pages[tt >> 4] * 16 + (tt & 15)) * 1024 + kvh * 128 + di;
        kb0 = *(const f32x4*)(Kp + a); kb1 = *(const f32x4*)(Kp + a + 4);
        vb0 = *(const f32x4*)(Vp + a); vb1 = *(const f32x4*)(Vp + a + 4);
      }
      update(ck, cv, (it + 1) * 32 + t0 < lim);
    }
  }

  if (w == 0) {                       // new decode token (position len-1)
    const float* kr = kn + ((size_t)b * 8 + kvh) * 128 + di;
    const float* vr = vn + ((size_t)b * 8 + kvh) * 128 + di;
    float ck[8], cv[8];
    #pragma unroll
    for (int j = 0; j < 8; ++j) { ck[j] = kr[j]; cv[j] = vr[j]; }
    update(ck, cv, sub == 0);
  }

  const int st = w * 4 + sub;
  if ((l & 15) == 0) {
    #pragma unroll
    for (int g = 0; g < 4; ++g) { mmS[st][g] = m[g]; msS[st][g] = se[g]; }
  }
  #pragma unroll
  for (int g = 0; g < 4; ++g)
    #pragma unroll
    for (int j = 0; j < 8; ++j) maccS[st][g][di + j] = acc[g][j];
  __syncthreads();

  const int g = t >> 7, dd = t & 127;
  float M = -INFINITY;
  #pragma unroll
  for (int s2 = 0; s2 < 32; ++s2) M = fmaxf(M, mmS[s2][g]);
  float den = 0.f, num = 0.f;
  for (int s2 = 0; s2 < 32; ++s2) {
    const float wg = exp2f(mmS[s2][g] - M);
    den += wg * msS[s2][g];
    num += wg * maccS[s2][g][dd];
  }
  ao[((size_t)b * 32 + kvh * 4 + g) * 128 + dd] = num / den;
}

// ---------------------------------------------------------------------------
extern "C" void kernel_launch(void* const* d_in, const int* in_sizes, int n_in,
                              void* d_out, int out_size, void* d_ws, size_t ws_size,
                              hipStream_t stream) {
  const float* x    = (const float*)d_in[0];
  const float* cosb = (const float*)d_in[1];
  const float* sinb = (const float*)d_in[2];
  const float* Wq   = (const float*)d_in[3];
  const float* Wk   = (const float*)d_in[4];
  const float* Wv   = (const float*)d_in[5];
  const float* Wo   = (const float*)d_in[6];
  const float* qw   = (const float*)d_in[7];
  const float* kw   = (const float*)d_in[8];
  const float* Kp   = (const float*)d_in[9];
  const float* Vp   = (const float*)d_in[10];
  const int*   pidx = (const int*)d_in[11];
  const int*   lens = (const int*)d_in[12];
  float* y = (float*)d_out;

  // ws layout (floats). op aliases qp (qp consumed by qkv epilogue first).
  float* ws = (float*)d_ws;
  float* qp = ws;                     // [5][32][4096] (op alias: [8][32][2560])
  float* kp = qp + 655360;            // [5][32][1024]
  float* vp = kp + 163840;            // [5][32][1024]
  float* qn = vp + 163840;            // [32][32][128]
  float* kn = qn + 131072;            // [32][8][128]
  float* vn = kn + 32768;             // [32][8][128]
  float* ao = vn + 32768;             // [32][32*128]
  int*   cnt = (int*)(ao + 131072);   // [88] last-block-done counters
  float* op = qp;                     // reuse
  (void)in_sizes; (void)n_in; (void)out_size; (void)ws_size;

  hipMemsetAsync(cnt, 0, 88 * sizeof(int), stream);
  qkv_gemm_f<<<dim3(96, 5), 256, 0, stream>>>(x, Wq, Wk, Wv, cosb, sinb, qw, kw,
                                              qp, kp, vp, qn, kn, vn, cnt);
  attn<<<256, 512, 0, stream>>>(Kp, Vp, qn, kn, vn, pidx, lens, ao);
  o_gemm_f<<<dim3(40, 8), 256, 0, stream>>>(ao, Wo, op, y, cnt);
}

// Round 13
// 99.283 us; speedup vs baseline: 2.2961x; 2.1517x over previous
//
#include <hip/hip_runtime.h>
#include <math.h>

// Problem constants (Qwen3-4B-like decode)
#define NB    32
#define HIDV  2560
#define HD    128
#define NQH   32
#define NKVH  8
// pool: (4096 pages, 16 slots, 8 kvh, 128 d)

typedef __bf16 bf16x8 __attribute__((ext_vector_type(8)));
typedef float  f32x4  __attribute__((ext_vector_type(4)));

__device__ __forceinline__ unsigned bfpack(float a, float b) {
  unsigned ua = __float_as_uint(a), ub = __float_as_uint(b);
  ua = (ua + 0x7FFFu + ((ua >> 16) & 1u)) >> 16;   // RNE to bf16
  ub = (ub + 0x7FFFu + ((ub >> 16) & 1u)) >> 16;
  return ua | (ub << 16);
}

// ---------------------------------------------------------------------------
// Partial GEMM body (R7-proven): P[kc0][b][f] = 2 slabs of 256 K each.
// ---------------------------------------------------------------------------
__device__ __forceinline__ void gemm_body(
    const float* __restrict__ X, const float* __restrict__ W,
    float* __restrict__ P, int N, int K, int f0, int kc0, int slabs, int t,
    unsigned short* Wl, unsigned short* Xl) {
  const int w = t >> 6, l = t & 63;
  const int rA = l & 15, kq = l >> 4;
  f32x4 acc0 = {0.f, 0.f, 0.f, 0.f}, acc1 = {0.f, 0.f, 0.f, 0.f};

  for (int s = 0; s < slabs; ++s) {
    const int kc = kc0 * slabs + s;
    if (s) __syncthreads();
    const float* Wg = W + (size_t)f0 * K + (size_t)kc * 256;
    #pragma unroll
    for (int i = 0; i < 16; ++i) {
      int idx = i * 256 + t;
      int row = idx >> 6, c4 = idx & 63;
      float4 w4 = *(const float4*)(Wg + (size_t)row * K + c4 * 4);
      *(uint2*)((char*)Wl + row * 528 + c4 * 8) =
          make_uint2(bfpack(w4.x, w4.y), bfpack(w4.z, w4.w));
    }
    const float* Xg = X + (size_t)kc * 256;
    #pragma unroll
    for (int i = 0; i < 8; ++i) {
      int idx = i * 256 + t;
      int row = idx >> 6, c4 = idx & 63;
      float4 x4 = *(const float4*)(Xg + (size_t)row * K + c4 * 4);
      *(uint2*)((char*)Xl + row * 528 + c4 * 8) =
          make_uint2(bfpack(x4.x, x4.y), bfpack(x4.z, x4.w));
    }
    __syncthreads();

    const char* pa0 = (const char*)Xl + rA * 528 + kq * 16;
    const char* pa1 = pa0 + 16 * 528;
    const char* pb  = (const char*)Wl + (w * 16 + rA) * 528 + kq * 16;
    #pragma unroll
    for (int ks = 0; ks < 8; ++ks) {
      bf16x8 a0 = *(const bf16x8*)(pa0 + ks * 64);
      bf16x8 a1 = *(const bf16x8*)(pa1 + ks * 64);
      bf16x8 bb = *(const bf16x8*)(pb  + ks * 64);
      acc0 = __builtin_amdgcn_mfma_f32_16x16x32_bf16(a0, bb, acc0, 0, 0, 0);
      acc1 = __builtin_amdgcn_mfma_f32_16x16x32_bf16(a1, bb, acc1, 0, 0, 0);
    }
  }
  const int fcol = f0 + w * 16 + rA;   // C/D: col=lane&15, row=(lane>>4)*4+j
  float* Pr = P + ((size_t)kc0 * 32) * N + fcol;
  #pragma unroll
  for (int j = 0; j < 4; ++j) {
    int b0 = kq * 4 + j;
    Pr[(size_t)b0 * N]        = acc0[j];
    Pr[(size_t)(b0 + 16) * N] = acc1[j];
  }
}

// Fused QKV projection (R7 verbatim): grid (96, 5), chunk = 512 K (2 slabs).
__global__ __launch_bounds__(256) void qkv_gemm(
    const float* __restrict__ X, const float* __restrict__ Wq,
    const float* __restrict__ Wk, const float* __restrict__ Wv,
    float* __restrict__ qp, float* __restrict__ kp, float* __restrict__ vp) {
  __shared__ __align__(16) unsigned short Wl[64 * 264];
  __shared__ __align__(16) unsigned short Xl[32 * 264];
  const int bx = blockIdx.x;
  const float* W; float* P; int N, f0;
  if (bx < 64)      { W = Wq; P = qp; N = 4096; f0 = bx * 64; }
  else if (bx < 80) { W = Wk; P = kp; N = 1024; f0 = (bx - 64) * 64; }
  else              { W = Wv; P = vp; N = 1024; f0 = (bx - 80) * 64; }
  gemm_body(X, W, P, N, 2560, f0, blockIdx.y, 2, threadIdx.x, Wl, Xl);
}

// ---------------------------------------------------------------------------
// o_proj GEMM with atomicAdd epilogue (no oreduce, no fences, no counters).
// grid (40, 8), block 256. y must be zeroed before this kernel (memset node).
// Each K-chunk block adds its partial directly; 8 adds per y element to
// distinct addresses -> contention-free device atomics.
// ---------------------------------------------------------------------------
__global__ __launch_bounds__(256) void o_gemm_a(
    const float* __restrict__ X, const float* __restrict__ W,
    float* __restrict__ y) {
  __shared__ __align__(16) unsigned short Wl[64 * 264];
  __shared__ __align__(16) unsigned short Xl[32 * 264];
  const int t = threadIdx.x;
  const int K = 4096, f0 = blockIdx.x * 64, kc0 = blockIdx.y;
  const int w = t >> 6, l = t & 63;
  const int rA = l & 15, kq = l >> 4;
  f32x4 acc0 = {0.f, 0.f, 0.f, 0.f}, acc1 = {0.f, 0.f, 0.f, 0.f};

  for (int s = 0; s < 2; ++s) {
    const int kc = kc0 * 2 + s;
    if (s) __syncthreads();
    const float* Wg = W + (size_t)f0 * K + (size_t)kc * 256;
    #pragma unroll
    for (int i = 0; i < 16; ++i) {
      int idx = i * 256 + t;
      int row = idx >> 6, c4 = idx & 63;
      float4 w4 = *(const float4*)(Wg + (size_t)row * K + c4 * 4);
      *(uint2*)((char*)Wl + row * 528 + c4 * 8) =
          make_uint2(bfpack(w4.x, w4.y), bfpack(w4.z, w4.w));
    }
    const float* Xg = X + (size_t)kc * 256;
    #pragma unroll
    for (int i = 0; i < 8; ++i) {
      int idx = i * 256 + t;
      int row = idx >> 6, c4 = idx & 63;
      float4 x4 = *(const float4*)(Xg + (size_t)row * K + c4 * 4);
      *(uint2*)((char*)Xl + row * 528 + c4 * 8) =
          make_uint2(bfpack(x4.x, x4.y), bfpack(x4.z, x4.w));
    }
    __syncthreads();

    const char* pa0 = (const char*)Xl + rA * 528 + kq * 16;
    const char* pa1 = pa0 + 16 * 528;
    const char* pb  = (const char*)Wl + (w * 16 + rA) * 528 + kq * 16;
    #pragma unroll
    for (int ks = 0; ks < 8; ++ks) {
      bf16x8 a0 = *(const bf16x8*)(pa0 + ks * 64);
      bf16x8 a1 = *(const bf16x8*)(pa1 + ks * 64);
      bf16x8 bb = *(const bf16x8*)(pb  + ks * 64);
      acc0 = __builtin_amdgcn_mfma_f32_16x16x32_bf16(a0, bb, acc0, 0, 0, 0);
      acc1 = __builtin_amdgcn_mfma_f32_16x16x32_bf16(a1, bb, acc1, 0, 0, 0);
    }
  }
  const int fcol = f0 + w * 16 + rA;
  float* Yr = y + fcol;
  #pragma unroll
  for (int j = 0; j < 4; ++j) {
    int b0 = kq * 4 + j;
    atomicAdd(&Yr[(size_t)b0 * 2560],        acc0[j]);
    atomicAdd(&Yr[(size_t)(b0 + 16) * 2560], acc1[j]);
  }
}

// ---------------------------------------------------------------------------
// Paged GQA decode attention with fused QKV-finalize prologue.
// grid = 256 (b*8+kvh), block = 512. Prologue (R4-verified, NO nt loads):
// reduce 5 K-split partials + RMSNorm + RoPE for this block's 4 q-heads and
// 1 k/v-head, in LDS aliased into maccS. Main loop = R7 depth-2 verbatim.
// New token folded from LDS (pool never mutated).
// ---------------------------------------------------------------------------
__global__ __launch_bounds__(512) void attn_f(
    const float* __restrict__ Kp, const float* __restrict__ Vp,
    const float* __restrict__ qp, const float* __restrict__ kp,
    const float* __restrict__ vp, const float* __restrict__ cosb,
    const float* __restrict__ sinb, const float* __restrict__ qw,
    const float* __restrict__ kw, const int* __restrict__ pidx,
    const int* __restrict__ lens, float* __restrict__ ao) {
  const int b = blockIdx.x >> 3, kvh = blockIdx.x & 7;
  const int t = threadIdx.x, w = t >> 6, l = t & 63;
  const int sub = l >> 4, di = (l & 15) * 8;
  __shared__ int pages[128];
  __shared__ float mmS[32][4], msS[32][4];
  __shared__ __align__(16) float maccS[32][4][128];
  // prologue scratch aliased into maccS[0..3] (wave-0-owned states only)
  float* qlds = &maccS[0][0][0];   // [4][128]
  float* klds = qlds + 512;        // [128]
  float* vlds = klds + 128;        // [128]
  float* rsum = vlds + 128;        // [10]

  if (t < 128) pages[t] = pidx[b * 128 + t];

  // ---- fused QKV finalize ----
  const int role = t >> 7, d = t & 127;
  float xq = 0.f;
  #pragma unroll
  for (int c = 0; c < 5; ++c)
    xq += qp[((size_t)c * 32 + b) * 4096 + (kvh * 4 + role) * 128 + d];
  float xk = 0.f, xv = 0.f;
  if (t < 128) {
    #pragma unroll
    for (int c = 0; c < 5; ++c)
      xk += kp[((size_t)c * 32 + b) * 1024 + kvh * 128 + d];
  } else if (t < 256) {
    #pragma unroll
    for (int c = 0; c < 5; ++c)
      xv += vp[((size_t)c * 32 + b) * 1024 + kvh * 128 + d];
  }
  float ssq = xq * xq;
  #pragma unroll
  for (int mk = 1; mk < 64; mk <<= 1) ssq += __shfl_xor(ssq, mk);
  if (l == 0) rsum[w] = ssq;
  if (t < 128) {
    float ssk = xk * xk;
    #pragma unroll
    for (int mk = 1; mk < 64; mk <<= 1) ssk += __shfl_xor(ssk, mk);
    if (l == 0) rsum[8 + w] = ssk;
  }
  __syncthreads();
  const float cb = cosb[b * 128 + d], sb = sinb[b * 128 + d];
  const float invq = rsqrtf((rsum[role * 2] + rsum[role * 2 + 1]) * (1.f / 128.f) + 1e-6f);
  const float xnq = xq * invq * qw[d];
  qlds[role * 128 + d] = xnq;
  float xnk = 0.f;
  if (t < 128) {
    const float invk = rsqrtf((rsum[8] + rsum[9]) * (1.f / 128.f) + 1e-6f);
    xnk = xk * invk * kw[d];
    klds[d] = xnk;
  } else if (t < 256) {
    vlds[d] = xv;
  }
  __syncthreads();
  const float rpq = qlds[role * 128 + (d ^ 64)];
  const float rpk = (t < 128) ? klds[d ^ 64] : 0.f;
  __syncthreads();
  qlds[role * 128 + d] = xnq * cb + ((d < 64) ? -rpq : rpq) * sb;
  if (t < 128) klds[d] = xnk * cb + ((d < 64) ? -rpk : rpk) * sb;
  __syncthreads();

  // ---- load q fragments (scaled), then barrier so no wave can overwrite
  //      qlds (via its maccS merge stores) before all waves read it ----
  const int len = lens[b], lim = len - 1;   // pool tokens: [0, lim)
  float qf[4][8];
  const float SC = 0.08838834764831845f * 1.4426950408889634f;
  #pragma unroll
  for (int g = 0; g < 4; ++g)
    #pragma unroll
    for (int j = 0; j < 8; ++j)
      qf[g][j] = qlds[g * 128 + di + j] * SC;
  __syncthreads();

  float m[4], se[4], acc[4][8];
  #pragma unroll
  for (int g = 0; g < 4; ++g) {
    m[g] = -INFINITY; se[g] = 0.f;
    #pragma unroll
    for (int j = 0; j < 8; ++j) acc[g][j] = 0.f;
  }

  const int t0 = w * 4 + sub;
  const int nit = (lim + 31) >> 5;

  auto update = [&](const float (&ck)[8], const float (&cv)[8], bool valid) {
    float s[4];
    #pragma unroll
    for (int g = 0; g < 4; ++g) {
      float d8 = 0.f;
      #pragma unroll
      for (int j = 0; j < 8; ++j) d8 += qf[g][j] * ck[j];
      s[g] = d8;
    }
    #pragma unroll
    for (int mk = 1; mk < 16; mk <<= 1) {
      #pragma unroll
      for (int g = 0; g < 4; ++g) s[g] += __shfl_xor(s[g], mk);
    }
    if (valid) {
      #pragma unroll
      for (int g = 0; g < 4; ++g) {
        const float sg = s[g];
        if (sg > m[g]) {
          const float scf = exp2f(m[g] - sg);
          m[g] = sg;
          se[g] = se[g] * scf + 1.f;
          #pragma unroll
          for (int j = 0; j < 8; ++j) acc[g][j] = acc[g][j] * scf + cv[j];
        } else {
          const float p = exp2f(sg - m[g]);
          se[g] += p;
          #pragma unroll
          for (int j = 0; j < 8; ++j) acc[g][j] += p * cv[j];
        }
      }
    }
  };

  // depth-2 software pipeline, static register names (A/B) — R7 verbatim
  f32x4 ka0, ka1, va0, va1, kb0, kb1, vb0, vb1;
  {
    int tt = min(t0, lim - 1);
    size_t a = ((size_t)pages[tt >> 4] * 16 + (tt & 15)) * 1024 + kvh * 128 + di;
    ka0 = *(const f32x4*)(Kp + a); ka1 = *(const f32x4*)(Kp + a + 4);
    va0 = *(const f32x4*)(Vp + a); va1 = *(const f32x4*)(Vp + a + 4);
  }
  if (nit > 1) {
    int tt = min(32 + t0, lim - 1);
    size_t a = ((size_t)pages[tt >> 4] * 16 + (tt & 15)) * 1024 + kvh * 128 + di;
    kb0 = *(const f32x4*)(Kp + a); kb1 = *(const f32x4*)(Kp + a + 4);
    vb0 = *(const f32x4*)(Vp + a); vb1 = *(const f32x4*)(Vp + a + 4);
  }
  for (int it = 0; it < nit; it += 2) {
    {
      const float ck[8] = {ka0[0], ka0[1], ka0[2], ka0[3], ka1[0], ka1[1], ka1[2], ka1[3]};
      const float cv[8] = {va0[0], va0[1], va0[2], va0[3], va1[0], va1[1], va1[2], va1[3]};
      if (it + 2 < nit) {
        int tt = min((it + 2) * 32 + t0, lim - 1);
        size_t a = ((size_t)pages[tt >> 4] * 16 + (tt & 15)) * 1024 + kvh * 128 + di;
        ka0 = *(const f32x4*)(Kp + a); ka1 = *(const f32x4*)(Kp + a + 4);
        va0 = *(const f32x4*)(Vp + a); va1 = *(const f32x4*)(Vp + a + 4);
      }
      update(ck, cv, it * 32 + t0 < lim);
    }
    if (it + 1 < nit) {
      const float ck[8] = {kb0[0], kb0[1], kb0[2], kb0[3], kb1[0], kb1[1], kb1[2], kb1[3]};
      const float cv[8] = {vb0[0], vb0[1], vb0[2], vb0[3], vb1[0], vb1[1], vb1[2], vb1[3]};
      if (it + 3 < nit) {
        int tt = min((it + 3) * 32 + t0, lim - 1);
        size_t a = ((size_t)pages[tt >> 4] * 16 + (tt & 15)) * 1024 + kvh * 128 + di;
        kb0 = *(const f32x4*)(Kp + a); kb1 = *(const f32x4*)(Kp + a + 4);
        vb0 = *(const f32x4*)(Vp + a); vb1 = *(const f32x4*)(Vp + a + 4);
      }
      update(ck, cv, (it + 1) * 32 + t0 < lim);
    }
  }

  // New decode token from LDS (klds/vlds = maccS[1] region, wave-0-owned;
  // wave 0 reads here BEFORE its own maccS stores — program-ordered safe).
  if (w == 0) {
    float ck[8], cv[8];
    #pragma unroll
    for (int j = 0; j < 8; ++j) { ck[j] = klds[di + j]; cv[j] = vlds[di + j]; }
    update(ck, cv, sub == 0);
  }

  // Merge the 32 partial states
  const int st = w * 4 + sub;
  if ((l & 15) == 0) {
    #pragma unroll
    for (int g = 0; g < 4; ++g) { mmS[st][g] = m[g]; msS[st][g] = se[g]; }
  }
  #pragma unroll
  for (int g = 0; g < 4; ++g)
    #pragma unroll
    for (int j = 0; j < 8; ++j) maccS[st][g][di + j] = acc[g][j];
  __syncthreads();

  const int g = t >> 7, dd = t & 127;
  float M = -INFINITY;
  #pragma unroll
  for (int s2 = 0; s2 < 32; ++s2) M = fmaxf(M, mmS[s2][g]);
  float den = 0.f, num = 0.f;
  for (int s2 = 0; s2 < 32; ++s2) {
    const float wg = exp2f(mmS[s2][g] - M);
    den += wg * msS[s2][g];
    num += wg * maccS[s2][g][dd];
  }
  ao[((size_t)b * 32 + kvh * 4 + g) * 128 + dd] = num / den;
}

// ---------------------------------------------------------------------------
extern "C" void kernel_launch(void* const* d_in, const int* in_sizes, int n_in,
                              void* d_out, int out_size, void* d_ws, size_t ws_size,
                              hipStream_t stream) {
  const float* x    = (const float*)d_in[0];
  const float* cosb = (const float*)d_in[1];
  const float* sinb = (const float*)d_in[2];
  const float* Wq   = (const float*)d_in[3];
  const float* Wk   = (const float*)d_in[4];
  const float* Wv   = (const float*)d_in[5];
  const float* Wo   = (const float*)d_in[6];
  const float* qw   = (const float*)d_in[7];
  const float* kw   = (const float*)d_in[8];
  const float* Kp   = (const float*)d_in[9];
  const float* Vp   = (const float*)d_in[10];
  const int*   pidx = (const int*)d_in[11];
  const int*   lens = (const int*)d_in[12];
  float* y = (float*)d_out;

  // ws layout (floats)
  float* ws = (float*)d_ws;
  float* qp = ws;                     // [5][32][4096]
  float* kp = qp + 655360;            // [5][32][1024]
  float* vp = kp + 163840;            // [5][32][1024]
  float* ao = vp + 163840;            // [32][32*128]
  (void)in_sizes; (void)n_in; (void)out_size; (void)ws_size;

  hipMemsetAsync(y, 0, (size_t)32 * 2560 * sizeof(float), stream);
  qkv_gemm<<<dim3(96, 5), 256, 0, stream>>>(x, Wq, Wk, Wv, qp, kp, vp);
  attn_f<<<256, 512, 0, stream>>>(Kp, Vp, qp, kp, vp, cosb, sinb, qw, kw,
                                  pidx, lens, ao);
  o_gemm_a<<<dim3(40, 8), 256, 0, stream>>>(ao, Wo, y);
}